// Round 12
// baseline (141.014 us; speedup 1.0000x reference)
//
#include <hip/hip_runtime.h>
#include <cmath>

typedef __bf16 bf16;
typedef __bf16 bf16x8 __attribute__((ext_vector_type(8)));
typedef float f32x4 __attribute__((ext_vector_type(4)));

#define SBAR() __builtin_amdgcn_sched_barrier(0)

// B=16, C_IN=256, H=W=64, C_OUT=256, 3x3, stride 1, pad 1, CURV=1

__device__ inline void gload16(const void* g, void* l) {
    __builtin_amdgcn_global_load_lds(
        (const __attribute__((address_space(1))) unsigned int*)g,
        (__attribute__((address_space(3))) unsigned int*)l, 16, 0, 0);
}

// ---------------------------------------------------------------------------
// Weight transform: z[k=c*9+tap][co] -> zt5[s=cc*9+tap][gran4][co256][8ch] bf16
__global__ void k_prep_zt(const float* __restrict__ z, bf16* __restrict__ zt5) {
    int s = blockIdx.x;                // 72 = cc*9 + tap, cc in 0..7 (32ch)
    int cc = s / 9, tap = s % 9;
    int co = threadIdx.x;
#pragma unroll
    for (int g = 0; g < 4; ++g) {
        bf16x8 pk;
#pragma unroll
        for (int e = 0; e < 8; ++e) {
            int c = cc * 32 + g * 8 + e;
            pk[e] = (bf16)z[(size_t)(c * 9 + tap) * 256 + co];
        }
        *(bf16x8*)(zt5 + ((size_t)(s * 4 + g) * 256 + co) * 8) = pk;
    }
}

// Column constants
__global__ void k_prep_cols(const float* __restrict__ z, const float* __restrict__ r,
                            float* __restrict__ zn, float* __restrict__ ch,
                            float* __restrict__ sh) {
    __shared__ float red[256];
    int co = blockIdx.x, t = threadIdx.x;
    float s = 0.f;
    for (int i = 0; i < 9; ++i) {
        float v = z[(size_t)(i * 256 + t) * 256 + co];
        s += v * v;
    }
    red[t] = s;
    __syncthreads();
    for (int off = 128; off >= 1; off >>= 1) {
        if (t < off) red[t] += red[t + off];
        __syncthreads();
    }
    if (t == 0) {
        zn[co] = fmaxf(sqrtf(red[0]), 1e-15f);
        float tc = 2.f * r[co];
        ch[co] = coshf(tc);
        sh[co] = sinhf(tc);
    }
}

// ---------------------------------------------------------------------------
// logmap0 * beta-ratio. Output layout is GRAN-MAJOR for the conv kernel's
// direct-global A reads: vt2[(b*32+g)][px4096][8ch] bf16 (g = channel/8).
__global__ void k_logmap(const float* __restrict__ x, unsigned int* __restrict__ vt_u,
                         float* __restrict__ sq, float Rbeta) {
    __shared__ float tile[256][33];
    __shared__ float red[8][32];
    __shared__ float afac[32];
    int tid = threadIdx.x;
    int blk = blockIdx.x;
    int b = blk >> 7;
    int pix0 = (blk & 127) << 5;

    for (int it = 0; it < 32; ++it) {
        int c = it * 8 + (tid >> 5);
        int p = tid & 31;
        tile[c][p] = x[((size_t)b * 256 + c) * 4096 + pix0 + p];
    }
    __syncthreads();

    {
        int part = tid >> 5, p = tid & 31;
        float s = 0.f;
        for (int i = 0; i < 32; ++i) {
            float v = tile[part * 32 + i][p];
            s += v * v;
        }
        red[part][p] = s;
    }
    __syncthreads();
    if (tid < 32) {
        float n2 = 0.f;
        for (int i = 0; i < 8; ++i) n2 += red[i][tid];
        float n = sqrtf(n2);
        float nc = fmaxf(n, 1e-15f);
        float a = atanhf(fminf(nc, 0.9999999f)) / nc * Rbeta;
        afac[tid] = a;
        sq[(size_t)b * 4096 + pix0 + tid] = a * a * n2;
    }
    __syncthreads();

    // gran-major pack: u32 index = ((b*32+g)*4096 + px)*4 + q, ch pair = g*8+2q
    for (int it = 0; it < 16; ++it) {
        int idx = it * 256 + tid;
        int q = idx & 3;
        int p = (idx >> 2) & 31;
        int g = idx >> 7;
        int cp = g * 4 + q;
        float a = afac[p];
        float v0 = a * tile[2 * cp][p];
        float v1 = a * tile[2 * cp + 1][p];
        union { bf16 h[2]; unsigned int u; } pk;
        pk.h[0] = (bf16)v0;
        pk.h[1] = (bf16)v1;
        vt_u[((size_t)(b * 32 + g) * 4096 + pix0 + p) * 4 + q] = pk.u;
    }
}

__global__ void k_boxsum(const float* __restrict__ sq, float* __restrict__ nusq) {
    int idx = blockIdx.x * 256 + threadIdx.x;
    int b = idx >> 12, hw = idx & 4095, h = hw >> 6, w = hw & 63;
    const float* s = sq + ((size_t)b << 12);
    float acc = 0.f;
    for (int dh = -1; dh <= 1; ++dh) {
        int hh = h + dh;
        if ((unsigned)hh >= 64u) continue;
        for (int dw = -1; dw <= 1; ++dw) {
            int ww = w + dw;
            if ((unsigned)ww >= 64u) continue;
            acc += s[hh * 64 + ww];
        }
    }
    nusq[idx] = acc;
}

// ---------------------------------------------------------------------------
// Fused implicit-GEMM conv + hyperbolic FC epilogue.
// Round-11 lesson: LDS pipe (~85-128 B/cyc/CU measured) was ~70% busy at
// 96 KB/stage/CU -- the binding resource. This version removes A from LDS:
//   A: direct global->reg from gran-major vt2 (coalesced dwordx4, L1-resident
//      working set, compile-time dh/dw immediates on 3 clamped row pointers,
//      1-stage prefetch, lane-0-clamped left base + cndmask for w edges).
//   B: LDS triple-buffer (1 barrier/stage, no trailing barrier), pad 4128
//      (lk bank offsets 0/8/16/24). LDS traffic halves to 48 KB/stage/CU.
//   Uniform vmcnt(6) = B(s+1)2 + A(s+1)4 newest in FIFO. SBAR-fenced.
__global__ void
__attribute__((amdgpu_flat_work_group_size(512, 512)))
__attribute__((amdgpu_waves_per_eu(4, 4)))
k_hconv(const bf16* __restrict__ vt2, const bf16* __restrict__ zt5,
        const float* __restrict__ nusq,
        const float* __restrict__ znp, const float* __restrict__ chp,
        const float* __restrict__ shp, float* __restrict__ out) {
    __shared__ __align__(1024) char Bsb[3][16512];   // 4 gran x 4128 B each
    __shared__ float s_lds[128], lam_lds[128];
    __shared__ float red[128][4];

    int tid = threadIdx.x;
    int bid = blockIdx.x;
    int bh = ((bid & 7) << 6) | (bid >> 3);   // XCD-bijective: 512 = 8 x 64
    int b = bh >> 5, h0 = (bh & 31) << 1;

    if (tid < 128) {
        int h = h0 + (tid >> 6), w = tid & 63;
        float q = nusq[((size_t)b << 12) + h * 64 + w];
        float ncl = fmaxf(sqrtf(q), 1e-15f);
        float p = __expf(2.f * ncl);
        float tt = (p - 1.f) / (p + 1.f);        // tanh(ncl)
        s_lds[tid] = tt / ncl;                   // expmap scale
        lam_lds[tid] = 2.f / (1.f - tt * tt);
    }

    int wave = tid >> 6, lane = tid & 63;
    int wn = wave & 3, wm = wave >> 2;    // wm row 0..1, wn co-quarter 0..3
    int lrow = lane & 15, lk = lane >> 4;

    f32x4 acc[4][4];
#pragma unroll
    for (int m = 0; m < 4; ++m)
#pragma unroll
        for (int n = 0; n < 4; ++n) acc[m][n] = (f32x4){0.f, 0.f, 0.f, 0.f};

    bf16x8 zf;
#pragma unroll
    for (int e = 0; e < 8; ++e) zf[e] = (bf16)0.0f;

    // A row pointers: plane (b*32 + cc*4 + lk), row clamp(h0+wm-1+j), px lrow.
    const bf16* Aptr[3];
#pragma unroll
    for (int j = 0; j < 3; ++j) {
        int hj = h0 + wm - 1 + j;
        hj = hj < 0 ? 0 : (hj > 63 ? 63 : hj);
        Aptr[j] = vt2 + (size_t)(b * 32 + lk) * 32768 + hj * 512 + lrow * 8;
    }
    const int dL = (lrow == 0) ? 0 : -16;     // left-edge byte delta (lane0 clamped)
    const bool okL = (lrow != 0);             // w'=-1 valid only for lrow>0
    const bool okR = (lrow != 15);            // w'=64 zero for lane 15 (m=3,dw=+1)

    // stage B stage snext into buffer dst: 16 KB linear; 2 loads/wave
    auto stageB = [&](char* dst, int snext) {
#pragma unroll
        for (int it = 0; it < 2; ++it) {
            int u = wave * 2 + it;
            gload16((const char*)zt5 + (size_t)snext * 16384 + u * 1024 + lane * 16,
                    dst + (u >> 2) * 4128 + (u & 3) * 1024);
        }
    };

    // prologue: B(0) -> buf0, A(0) (tap0: dh=-1 -> j=0, dw=-1) -> regs
    stageB((char*)Bsb[0], 0);
    bf16x8 ap[4];
#pragma unroll
    for (int m = 0; m < 4; ++m)
        ap[m] = (m == 0) ? *(const bf16x8*)((const char*)Aptr[0] + dL)
                         : *(const bf16x8*)(Aptr[0] + (m * 16 - 1) * 8);
    __syncthreads();                      // drains prologue; s_lds visible
    SBAR();

    const int bOff = lk * 4128 + wn * 1024 + lrow * 16;

#pragma unroll 1
    for (int cc = 0; cc < 8; ++cc) {
#pragma unroll
        for (int tap = 0; tap < 9; ++tap) {
            const int s = cc * 9 + tap;
            const bool lastS = (s == 71);

            // ---- issue region ----
            if (tap == 8) {               // advance planes to cc+1 before prefetch
#pragma unroll
                for (int j = 0; j < 3; ++j) Aptr[j] += 4 * 32768;
            }
            if (!lastS) stageB((char*)Bsb[(tap + 1) % 3], s + 1);
            bf16x8 an[4];
            {
                const int nt = (tap == 8) ? 0 : tap + 1;
                const int ndh = nt / 3 - 1, ndw = nt % 3 - 1, nj = ndh + 1;
#pragma unroll
                for (int m = 0; m < 4; ++m)
                    an[m] = (ndw == -1 && m == 0)
                        ? *(const bf16x8*)((const char*)Aptr[nj] + dL)
                        : *(const bf16x8*)(Aptr[nj] + (m * 16 + ndw) * 8);
            }
            SBAR();
            if (!lastS) { asm volatile("s_waitcnt vmcnt(6)" ::: "memory"); }
            else        { asm volatile("s_waitcnt vmcnt(4)" ::: "memory"); }
            SBAR();
            asm volatile("s_barrier" ::: "memory");   // B(s) visible to all
            SBAR();

            // ---- compute stage s ----
            const int dh = tap / 3 - 1, dw = tap % 3 - 1;
            int hh = h0 + wm + dh;
            if ((unsigned)hh < 64u) {                 // wave-uniform skip
                bf16x8 a0 = ap[0], a1 = ap[1], a2 = ap[2], a3 = ap[3];
                if (dw == -1) a0 = okL ? a0 : zf;
                if (dw == 1)  a3 = okR ? a3 : zf;
                const char* Bp = (const char*)Bsb[tap % 3] + bOff;
                bf16x8 b0 = *(const bf16x8*)(Bp);
                bf16x8 b1 = *(const bf16x8*)(Bp + 256);
                bf16x8 b2 = *(const bf16x8*)(Bp + 512);
                bf16x8 b3 = *(const bf16x8*)(Bp + 768);
                __builtin_amdgcn_s_setprio(1);
                acc[0][0] = __builtin_amdgcn_mfma_f32_16x16x32_bf16(a0, b0, acc[0][0], 0, 0, 0);
                acc[1][0] = __builtin_amdgcn_mfma_f32_16x16x32_bf16(a1, b0, acc[1][0], 0, 0, 0);
                acc[2][0] = __builtin_amdgcn_mfma_f32_16x16x32_bf16(a2, b0, acc[2][0], 0, 0, 0);
                acc[3][0] = __builtin_amdgcn_mfma_f32_16x16x32_bf16(a3, b0, acc[3][0], 0, 0, 0);
                acc[0][1] = __builtin_amdgcn_mfma_f32_16x16x32_bf16(a0, b1, acc[0][1], 0, 0, 0);
                acc[1][1] = __builtin_amdgcn_mfma_f32_16x16x32_bf16(a1, b1, acc[1][1], 0, 0, 0);
                acc[2][1] = __builtin_amdgcn_mfma_f32_16x16x32_bf16(a2, b1, acc[2][1], 0, 0, 0);
                acc[3][1] = __builtin_amdgcn_mfma_f32_16x16x32_bf16(a3, b1, acc[3][1], 0, 0, 0);
                acc[0][2] = __builtin_amdgcn_mfma_f32_16x16x32_bf16(a0, b2, acc[0][2], 0, 0, 0);
                acc[1][2] = __builtin_amdgcn_mfma_f32_16x16x32_bf16(a1, b2, acc[1][2], 0, 0, 0);
                acc[2][2] = __builtin_amdgcn_mfma_f32_16x16x32_bf16(a2, b2, acc[2][2], 0, 0, 0);
                acc[3][2] = __builtin_amdgcn_mfma_f32_16x16x32_bf16(a3, b2, acc[3][2], 0, 0, 0);
                acc[0][3] = __builtin_amdgcn_mfma_f32_16x16x32_bf16(a0, b3, acc[0][3], 0, 0, 0);
                acc[1][3] = __builtin_amdgcn_mfma_f32_16x16x32_bf16(a1, b3, acc[1][3], 0, 0, 0);
                acc[2][3] = __builtin_amdgcn_mfma_f32_16x16x32_bf16(a2, b3, acc[2][3], 0, 0, 0);
                acc[3][3] = __builtin_amdgcn_mfma_f32_16x16x32_bf16(a3, b3, acc[3][3], 0, 0, 0);
                __builtin_amdgcn_s_setprio(0);
            }
            SBAR();
#pragma unroll
            for (int m = 0; m < 4; ++m) ap[m] = an[m];   // rotate prefetch
        }
    }

    // ---------------- epilogue (fast transcendental forms) ----------------
    float cz[4], sh4[4], tz[4];
#pragma unroll
    for (int n = 0; n < 4; ++n) {
        int co = wn * 64 + n * 16 + lrow;
        float zn = znp[co];
        cz[n] = chp[co] / zn;
        sh4[n] = shp[co];
        tz[n] = 2.f * zn;
    }

#pragma unroll
    for (int m = 0; m < 4; ++m) {
#pragma unroll
        for (int r = 0; r < 4; ++r) {
            int wp = wm * 64 + m * 16 + 4 * lk + r;   // block-local px slot
            float s = s_lds[wp], lam = lam_lds[wp];
            float lm1 = lam - 1.f;
            float psum = 0.f;
#pragma unroll
            for (int n = 0; n < 4; ++n) {
                float xz = s * acc[m][n][r];
                float inner = lam * xz * cz[n] - lm1 * sh4[n];
                float as = __logf(inner + sqrtf(inner * inner + 1.f)); // asinh
                float p = __expf(tz[n] * as);
                float w = 0.5f * (p - __builtin_amdgcn_rcpf(p));       // sinh
                acc[m][n][r] = w;
                psum += w * w;
            }
            psum += __shfl_xor(psum, 1);
            psum += __shfl_xor(psum, 2);
            psum += __shfl_xor(psum, 4);
            psum += __shfl_xor(psum, 8);
            if (lrow == 0) red[wp][wn] = psum;
        }
    }
    __syncthreads();

    float dinv[4][4];
#pragma unroll
    for (int m = 0; m < 4; ++m)
#pragma unroll
        for (int r = 0; r < 4; ++r) {
            int wp = wm * 64 + m * 16 + 4 * lk + r;
            float tot = (red[wp][0] + red[wp][1]) + (red[wp][2] + red[wp][3]);
            dinv[m][r] = __builtin_amdgcn_rcpf(1.f + sqrtf(1.f + tot));
        }

    float* ob = out + (size_t)b * 256 * 4096 + (h0 + wm) * 64;
#pragma unroll
    for (int m = 0; m < 4; ++m) {
#pragma unroll
        for (int n = 0; n < 4; ++n) {
            int co = wn * 64 + n * 16 + lrow;
            f32x4 o;
#pragma unroll
            for (int r = 0; r < 4; ++r) o[r] = acc[m][n][r] * dinv[m][r];
            *(f32x4*)(ob + (size_t)co * 4096 + m * 16 + 4 * lk) = o;
        }
    }
}

// ---------------------------------------------------------------------------
extern "C" void kernel_launch(void* const* d_in, const int* in_sizes, int n_in,
                              void* d_out, int out_size, void* d_ws, size_t ws_size,
                              hipStream_t stream) {
    const float* x = (const float*)d_in[0];   // [16,256,64,64]
    const float* z = (const float*)d_in[1];   // [2304,256]
    const float* r = (const float*)d_in[2];   // [256]
    float* out = (float*)d_out;               // [16,256,64,64]

    char* ws = (char*)d_ws;
    bf16* vt2 = (bf16*)ws;                        // 33,554,432 B (gran-major)
    float* sq = (float*)(ws + 33554432);
    float* nusq = (float*)(ws + 33816576);
    bf16* zt5 = (bf16*)(ws + 34078720);           // 72*16KB = 1,179,648 B
    float* zn = (float*)(ws + 35258368);
    float* ch = (float*)(ws + 35259392);
    float* sh = (float*)(ws + 35260416);
    if (ws_size < 35261440) return;

    double bni = lgamma(128.0) + lgamma(0.5) - lgamma(128.5);
    double bn = lgamma(1152.0) + lgamma(0.5) - lgamma(1152.5);
    float Rbeta = (float)exp(bn - bni);

    k_prep_zt<<<72, 256, 0, stream>>>(z, zt5);
    k_prep_cols<<<256, 256, 0, stream>>>(z, r, zn, ch, sh);
    k_logmap<<<2048, 256, 0, stream>>>(x, (unsigned int*)vt2, sq, Rbeta);
    k_boxsum<<<256, 256, 0, stream>>>(sq, nusq);
    k_hconv<<<512, 512, 0, stream>>>(vt2, zt5, nusq, zn, ch, sh, out);
}

// Round 13
// 131.335 us; speedup vs baseline: 1.0737x; 1.0737x over previous
//
#include <hip/hip_runtime.h>
#include <cmath>

typedef __bf16 bf16;
typedef __bf16 bf16x8 __attribute__((ext_vector_type(8)));
typedef float f32x4 __attribute__((ext_vector_type(4)));

#define SBAR() __builtin_amdgcn_sched_barrier(0)

// B=16, C_IN=256, H=W=64, C_OUT=256, 3x3, stride 1, pad 1, CURV=1

__device__ inline void gload16(const void* g, void* l) {
    __builtin_amdgcn_global_load_lds(
        (const __attribute__((address_space(1))) unsigned int*)g,
        (__attribute__((address_space(3))) unsigned int*)l, 16, 0, 0);
}

// ---------------------------------------------------------------------------
// Weight transform: z[k=c*9+tap][co] -> zt6[s=cc*9+tap][co256][gran4][8ch]
// bf16. A wave's B-frag load (16 co x 4 gran x 16B) is one contiguous 1 KB.
__global__ void k_prep_zt(const float* __restrict__ z, bf16* __restrict__ zt6) {
    int s = blockIdx.x;                // 72 = cc*9 + tap, cc in 0..7 (32ch)
    int cc = s / 9, tap = s % 9;
    int co = threadIdx.x;
#pragma unroll
    for (int g = 0; g < 4; ++g) {
        bf16x8 pk;
#pragma unroll
        for (int e = 0; e < 8; ++e) {
            int c = cc * 32 + g * 8 + e;
            pk[e] = (bf16)z[(size_t)(c * 9 + tap) * 256 + co];
        }
        *(bf16x8*)(zt6 + ((size_t)(s * 256 + co) * 4 + g) * 8) = pk;
    }
}

// Column constants
__global__ void k_prep_cols(const float* __restrict__ z, const float* __restrict__ r,
                            float* __restrict__ zn, float* __restrict__ ch,
                            float* __restrict__ sh) {
    __shared__ float red[256];
    int co = blockIdx.x, t = threadIdx.x;
    float s = 0.f;
    for (int i = 0; i < 9; ++i) {
        float v = z[(size_t)(i * 256 + t) * 256 + co];
        s += v * v;
    }
    red[t] = s;
    __syncthreads();
    for (int off = 128; off >= 1; off >>= 1) {
        if (t < off) red[t] += red[t + off];
        __syncthreads();
    }
    if (t == 0) {
        zn[co] = fmaxf(sqrtf(red[0]), 1e-15f);
        float tc = 2.f * r[co];
        ch[co] = coshf(tc);
        sh[co] = sinhf(tc);
    }
}

// ---------------------------------------------------------------------------
// logmap0 * beta-ratio, transpose [B,C,HW] -> vt[B,HW,C] bf16 (px-major),
// and per-pixel sq = sum_c v^2 (fp32).   [round-11 version]
__global__ void k_logmap(const float* __restrict__ x, unsigned int* __restrict__ vt_u,
                         float* __restrict__ sq, float Rbeta) {
    __shared__ float tile[256][33];
    __shared__ float red[8][32];
    __shared__ float afac[32];
    int tid = threadIdx.x;
    int blk = blockIdx.x;
    int b = blk >> 7;
    int pix0 = (blk & 127) << 5;

    for (int it = 0; it < 32; ++it) {
        int c = it * 8 + (tid >> 5);
        int p = tid & 31;
        tile[c][p] = x[((size_t)b * 256 + c) * 4096 + pix0 + p];
    }
    __syncthreads();

    {
        int part = tid >> 5, p = tid & 31;
        float s = 0.f;
        for (int i = 0; i < 32; ++i) {
            float v = tile[part * 32 + i][p];
            s += v * v;
        }
        red[part][p] = s;
    }
    __syncthreads();
    if (tid < 32) {
        float n2 = 0.f;
        for (int i = 0; i < 8; ++i) n2 += red[i][tid];
        float n = sqrtf(n2);
        float nc = fmaxf(n, 1e-15f);
        float a = atanhf(fminf(nc, 0.9999999f)) / nc * Rbeta;
        afac[tid] = a;
        sq[(size_t)b * 4096 + pix0 + tid] = a * a * n2;
    }
    __syncthreads();

    for (int it = 0; it < 16; ++it) {
        int idx = it * 256 + tid;
        int p = idx >> 7;
        int cp = idx & 127;
        float a = afac[p];
        float v0 = a * tile[2 * cp][p];
        float v1 = a * tile[2 * cp + 1][p];
        union { bf16 h[2]; unsigned int u; } pk;
        pk.h[0] = (bf16)v0;
        pk.h[1] = (bf16)v1;
        vt_u[((size_t)b * 4096 + pix0 + p) * 128 + cp] = pk.u;
    }
}

__global__ void k_boxsum(const float* __restrict__ sq, float* __restrict__ nusq) {
    int idx = blockIdx.x * 256 + threadIdx.x;
    int b = idx >> 12, hw = idx & 4095, h = hw >> 6, w = hw & 63;
    const float* s = sq + ((size_t)b << 12);
    float acc = 0.f;
    for (int dh = -1; dh <= 1; ++dh) {
        int hh = h + dh;
        if ((unsigned)hh >= 64u) continue;
        for (int dw = -1; dw <= 1; ++dw) {
            int ww = w + dw;
            if ((unsigned)ww >= 64u) continue;
            acc += s[hh * 64 + ww];
        }
    }
    nusq[idx] = acc;
}

// ---------------------------------------------------------------------------
// Fused implicit-GEMM conv + hyperbolic FC epilogue.
// Round-12 lesson: A-from-global spilled + thrashed L1 -> reverted (A stays
// in LDS, round-11 halo layout). Round-11 lesson: LDS pipe was the binding
// resource (11.8 MB/CU). This version moves B global->REGISTERS (wave-private
// 1-stage prefetch, bA/bB ping-pong, static parity via cc-unroll-2):
//   - LDS traffic drops ~60% (B reads+writes gone); LDS holds A only (17 KB).
//   - Per-stage barrier eliminated: 2 barriers/cc for the A restage only.
//   - B loads are compiler-tracked (auto vmcnt); manual vmcnt(4)+s_barrier at
//     tap0 covers the A gload_lds (FIFO: A older than B(s+1)).
__global__ void
__attribute__((amdgpu_flat_work_group_size(512, 512)))
__attribute__((amdgpu_waves_per_eu(4, 4)))
k_hconv(const bf16* __restrict__ vt, const bf16* __restrict__ zt6,
        const float* __restrict__ nusq,
        const float* __restrict__ znp, const float* __restrict__ chp,
        const float* __restrict__ shp, float* __restrict__ out) {
    __shared__ __align__(1024) char Asb[16896];      // 16 units x 1056 B
    __shared__ float s_lds[128], lam_lds[128];
    __shared__ float red[128][4];

    int tid = threadIdx.x;
    int bid = blockIdx.x;
    int bh = ((bid & 7) << 6) | (bid >> 3);   // XCD-bijective: 512 = 8 x 64
    int b = bh >> 5, h0 = (bh & 31) << 1;

    // zero halo slots (0 and 65) of the 16 A units, once
    if (tid < 32) {
        int u = tid >> 1, side = tid & 1;
        *(f32x4*)(Asb + u * 1056 + side * 1040) = (f32x4){0.f, 0.f, 0.f, 0.f};
    }

    if (tid >= 128 && tid < 256) {
        int t = tid - 128;
        int h = h0 + (t >> 6), w = t & 63;
        float q = nusq[((size_t)b << 12) + h * 64 + w];
        float ncl = fmaxf(sqrtf(q), 1e-15f);
        float p = __expf(2.f * ncl);
        float tt = (p - 1.f) / (p + 1.f);        // tanh(ncl)
        s_lds[t] = tt / ncl;                     // expmap scale
        lam_lds[t] = 2.f / (1.f - tt * tt);
    }

    int wave = tid >> 6, lane = tid & 63;
    int wn = wave & 3, wm = wave >> 2;    // wm row 0..1, wn co-quarter 0..3
    int lrow = lane & 15, lk = lane >> 4;

    f32x4 acc[4][4];
#pragma unroll
    for (int m = 0; m < 4; ++m)
#pragma unroll
        for (int n = 0; n < 4; ++n) acc[m][n] = (f32x4){0.f, 0.f, 0.f, 0.f};

    const bf16* vb = vt + (((size_t)b) << 12) * 256;

    // stage A chunk ccn: 16 units (r4 x g4); 2 gload_lds/wave
    auto stageA = [&](int ccn) {
#pragma unroll
        for (int it = 0; it < 2; ++it) {
            int u = wave * 2 + it;
            int r = u >> 2, g = u & 3;
            int hr = h0 - 1 + r;
            hr = hr < 0 ? 0 : (hr > 63 ? 63 : hr);   // clamped rows never read
            const bf16* gp = vb + ((size_t)(hr * 64 + lane)) * 256 + ccn * 32 + g * 8;
            gload16(gp, Asb + u * 1056 + 16);
        }
    };

    // B: wave-private global->reg. Wave reads 1 KB contiguous per frag set.
    const bf16* bp = zt6 + ((size_t)(wn * 64 + lrow) * 4 + lk) * 8;
    bf16x8 bA[4], bB[4];
#pragma unroll
    for (int n = 0; n < 4; ++n) bA[n] = *(const bf16x8*)(bp + n * 512);
    const bf16* bnp = bp + 8192;          // points at stage 1

    stageA(0);
    __syncthreads();                      // drains prologue; s_lds visible
    SBAR();

    const char* ApB = Asb + lk * 1056 + lrow * 16;

#define STAGE(CCV, TAP, CUR, NXT)                                            \
    {                                                                        \
        const int s_ = (CCV) * 9 + (TAP);                                    \
        if (s_ < 71) {                                                       \
            NXT[0] = *(const bf16x8*)(bnp);                                  \
            NXT[1] = *(const bf16x8*)(bnp + 512);                            \
            NXT[2] = *(const bf16x8*)(bnp + 1024);                           \
            NXT[3] = *(const bf16x8*)(bnp + 1536);                           \
            bnp += 8192;                                                     \
        }                                                                    \
        SBAR();                                                              \
        if ((TAP) == 0) {                                                    \
            asm volatile("s_waitcnt vmcnt(4)" ::: "memory");                 \
            SBAR();                                                          \
            asm volatile("s_barrier" ::: "memory");   /* A[cc] ready */      \
            SBAR();                                                          \
        }                                                                    \
        {                                                                    \
            const int dh_ = (TAP) / 3 - 1, dw_ = (TAP) % 3 - 1;              \
            int hh_ = h0 + wm + dh_;                                         \
            if ((unsigned)hh_ < 64u) {                                       \
                const char* Ap_ = ApB + (wm + dh_ + 1) * 4224 + (dw_ + 1) * 16; \
                bf16x8 a0 = *(const bf16x8*)(Ap_);                           \
                bf16x8 a1 = *(const bf16x8*)(Ap_ + 256);                     \
                bf16x8 a2 = *(const bf16x8*)(Ap_ + 512);                     \
                bf16x8 a3 = *(const bf16x8*)(Ap_ + 768);                     \
                __builtin_amdgcn_s_setprio(1);                               \
                acc[0][0] = __builtin_amdgcn_mfma_f32_16x16x32_bf16(a0, CUR[0], acc[0][0], 0, 0, 0); \
                acc[1][0] = __builtin_amdgcn_mfma_f32_16x16x32_bf16(a1, CUR[0], acc[1][0], 0, 0, 0); \
                acc[2][0] = __builtin_amdgcn_mfma_f32_16x16x32_bf16(a2, CUR[0], acc[2][0], 0, 0, 0); \
                acc[3][0] = __builtin_amdgcn_mfma_f32_16x16x32_bf16(a3, CUR[0], acc[3][0], 0, 0, 0); \
                acc[0][1] = __builtin_amdgcn_mfma_f32_16x16x32_bf16(a0, CUR[1], acc[0][1], 0, 0, 0); \
                acc[1][1] = __builtin_amdgcn_mfma_f32_16x16x32_bf16(a1, CUR[1], acc[1][1], 0, 0, 0); \
                acc[2][1] = __builtin_amdgcn_mfma_f32_16x16x32_bf16(a2, CUR[1], acc[2][1], 0, 0, 0); \
                acc[3][1] = __builtin_amdgcn_mfma_f32_16x16x32_bf16(a3, CUR[1], acc[3][1], 0, 0, 0); \
                acc[0][2] = __builtin_amdgcn_mfma_f32_16x16x32_bf16(a0, CUR[2], acc[0][2], 0, 0, 0); \
                acc[1][2] = __builtin_amdgcn_mfma_f32_16x16x32_bf16(a1, CUR[2], acc[1][2], 0, 0, 0); \
                acc[2][2] = __builtin_amdgcn_mfma_f32_16x16x32_bf16(a2, CUR[2], acc[2][2], 0, 0, 0); \
                acc[3][2] = __builtin_amdgcn_mfma_f32_16x16x32_bf16(a3, CUR[2], acc[3][2], 0, 0, 0); \
                acc[0][3] = __builtin_amdgcn_mfma_f32_16x16x32_bf16(a0, CUR[3], acc[0][3], 0, 0, 0); \
                acc[1][3] = __builtin_amdgcn_mfma_f32_16x16x32_bf16(a1, CUR[3], acc[1][3], 0, 0, 0); \
                acc[2][3] = __builtin_amdgcn_mfma_f32_16x16x32_bf16(a2, CUR[3], acc[2][3], 0, 0, 0); \
                acc[3][3] = __builtin_amdgcn_mfma_f32_16x16x32_bf16(a3, CUR[3], acc[3][3], 0, 0, 0); \
                __builtin_amdgcn_s_setprio(0);                               \
            }                                                                \
        }                                                                    \
        SBAR();                                                              \
        if ((TAP) == 8 && (CCV) < 7) {                                       \
            asm volatile("s_barrier" ::: "memory");   /* WAR: A reads done */ \
            SBAR();                                                          \
            stageA((CCV) + 1);                                               \
            SBAR();                                                          \
        }                                                                    \
    }

#pragma unroll 1
    for (int cc2 = 0; cc2 < 4; ++cc2) {
        const int c0 = cc2 * 2, c1 = c0 + 1;
        STAGE(c0, 0, bA, bB) STAGE(c0, 1, bB, bA) STAGE(c0, 2, bA, bB)
        STAGE(c0, 3, bB, bA) STAGE(c0, 4, bA, bB) STAGE(c0, 5, bB, bA)
        STAGE(c0, 6, bA, bB) STAGE(c0, 7, bB, bA) STAGE(c0, 8, bA, bB)
        STAGE(c1, 0, bB, bA) STAGE(c1, 1, bA, bB) STAGE(c1, 2, bB, bA)
        STAGE(c1, 3, bA, bB) STAGE(c1, 4, bB, bA) STAGE(c1, 5, bA, bB)
        STAGE(c1, 6, bB, bA) STAGE(c1, 7, bA, bB) STAGE(c1, 8, bB, bA)
    }
#undef STAGE

    // ---------------- epilogue (fast transcendental forms) ----------------
    float cz[4], sh4[4], tz[4];
#pragma unroll
    for (int n = 0; n < 4; ++n) {
        int co = wn * 64 + n * 16 + lrow;
        float zn = znp[co];
        cz[n] = chp[co] / zn;
        sh4[n] = shp[co];
        tz[n] = 2.f * zn;
    }

#pragma unroll
    for (int m = 0; m < 4; ++m) {
#pragma unroll
        for (int r = 0; r < 4; ++r) {
            int wp = wm * 64 + m * 16 + 4 * lk + r;   // block-local px slot
            float s = s_lds[wp], lam = lam_lds[wp];
            float lm1 = lam - 1.f;
            float psum = 0.f;
#pragma unroll
            for (int n = 0; n < 4; ++n) {
                float xz = s * acc[m][n][r];
                float inner = lam * xz * cz[n] - lm1 * sh4[n];
                float as = __logf(inner + sqrtf(inner * inner + 1.f)); // asinh
                float p = __expf(tz[n] * as);
                float w = 0.5f * (p - __builtin_amdgcn_rcpf(p));       // sinh
                acc[m][n][r] = w;
                psum += w * w;
            }
            psum += __shfl_xor(psum, 1);
            psum += __shfl_xor(psum, 2);
            psum += __shfl_xor(psum, 4);
            psum += __shfl_xor(psum, 8);
            if (lrow == 0) red[wp][wn] = psum;
        }
    }
    __syncthreads();

    float dinv[4][4];
#pragma unroll
    for (int m = 0; m < 4; ++m)
#pragma unroll
        for (int r = 0; r < 4; ++r) {
            int wp = wm * 64 + m * 16 + 4 * lk + r;
            float tot = (red[wp][0] + red[wp][1]) + (red[wp][2] + red[wp][3]);
            dinv[m][r] = __builtin_amdgcn_rcpf(1.f + sqrtf(1.f + tot));
        }

    float* ob = out + (size_t)b * 256 * 4096 + (h0 + wm) * 64;
#pragma unroll
    for (int m = 0; m < 4; ++m) {
#pragma unroll
        for (int n = 0; n < 4; ++n) {
            int co = wn * 64 + n * 16 + lrow;
            f32x4 o;
#pragma unroll
            for (int r = 0; r < 4; ++r) o[r] = acc[m][n][r] * dinv[m][r];
            *(f32x4*)(ob + (size_t)co * 4096 + m * 16 + 4 * lk) = o;
        }
    }
}

// ---------------------------------------------------------------------------
extern "C" void kernel_launch(void* const* d_in, const int* in_sizes, int n_in,
                              void* d_out, int out_size, void* d_ws, size_t ws_size,
                              hipStream_t stream) {
    const float* x = (const float*)d_in[0];   // [16,256,64,64]
    const float* z = (const float*)d_in[1];   // [2304,256]
    const float* r = (const float*)d_in[2];   // [256]
    float* out = (float*)d_out;               // [16,256,64,64]

    char* ws = (char*)d_ws;
    bf16* vt = (bf16*)ws;                         // 33,554,432 B (px-major)
    float* sq = (float*)(ws + 33554432);
    float* nusq = (float*)(ws + 33816576);
    bf16* zt6 = (bf16*)(ws + 34078720);           // 72*16KB = 1,179,648 B
    float* zn = (float*)(ws + 35258368);
    float* ch = (float*)(ws + 35259392);
    float* sh = (float*)(ws + 35260416);
    if (ws_size < 35261440) return;

    double bni = lgamma(128.0) + lgamma(0.5) - lgamma(128.5);
    double bn = lgamma(1152.0) + lgamma(0.5) - lgamma(1152.5);
    float Rbeta = (float)exp(bn - bni);

    k_prep_zt<<<72, 256, 0, stream>>>(z, zt6);
    k_prep_cols<<<256, 256, 0, stream>>>(z, r, zn, ch, sh);
    k_logmap<<<2048, 256, 0, stream>>>(x, (unsigned int*)vt, sq, Rbeta);
    k_boxsum<<<256, 256, 0, stream>>>(sq, nusq);
    k_hconv<<<512, 512, 0, stream>>>(vt, zt6, nusq, zn, ch, sh, out);
}